// Round 1
// baseline (513.251 us; speedup 1.0000x reference)
//
#include <hip/hip_runtime.h>

// Problem constants: x (N=64, C=256, T=64, V=50) fp32; H=16; 10 parts.
#define N_  64
#define C_  256
#define T_  64
#define V_  50
#define H_  16
#define NP_ 10
#define ROW_ (T_ * V_)          // 3200 floats per (n,c) row
#define NC_  (N_ * C_)          // 16384 rows
#define NPC_ (N_ * NP_ * C_)    // 163840 floats per ws array

// part of each source vertex v (compile-time folded in unrolled loop)
constexpr int PART_OF_V[V_] = {
    0,0,0,0, 3,3,3,3, 1,1,1,1, 4,4,4,4, 2,2,2,2, 0, 3,3, 1,1,
    5,5,5,5, 8,8,8,8, 6,6,6,6, 9,9,9,9, 7,7,7,7, 5, 8,8, 6,6};

// 1 / (T * |part p|); sizes = {5,6,4,6,4,5,6,4,6,4}
constexpr float INV_CNT[NP_] = {
    1.f/320, 1.f/384, 1.f/256, 1.f/384, 1.f/256,
    1.f/320, 1.f/384, 1.f/256, 1.f/384, 1.f/256};

// out column w -> source v (concat of PARTS) and part of w (runtime-indexed)
__device__ const int SRC_V[V_] = {
    0,1,2,3,20,  8,9,10,11,23,24,  16,17,18,19,  4,5,6,7,21,22,  12,13,14,15,
    25,26,27,28,45,  33,34,35,36,48,49,  41,42,43,44,  29,30,31,32,46,47,  37,38,39,40};
__device__ const int PART_W[V_] = {
    0,0,0,0,0, 1,1,1,1,1,1, 2,2,2,2, 3,3,3,3,3,3, 4,4,4,4,
    5,5,5,5,5, 6,6,6,6,6,6, 7,7,7,7, 8,8,8,8,8,8, 9,9,9,9};

// ---------------------------------------------------------------------------
// Kernel A: per-(n,c) row, per-part sum & max over (T, V_p).
// One wave per row; 4 waves per block.
// ---------------------------------------------------------------------------
__global__ __launch_bounds__(256) void reduce_kernel(
    const float* __restrict__ x,
    float* __restrict__ avg_out,     // [(n*10+p)*256 + c]
    float* __restrict__ max_out) {
    __shared__ float lds[4][ROW_];
    const int wave = threadIdx.x >> 6;
    const int lane = threadIdx.x & 63;
    const int row  = blockIdx.x * 4 + wave;          // n*256 + c

    // coalesced float4 stage: 800 float4 per row
    const float4* xr4 = (const float4*)(x + (size_t)row * ROW_);
    float4* l4 = (float4*)lds[wave];
    #pragma unroll
    for (int j = 0; j < 12; ++j) l4[lane + 64 * j] = xr4[lane + 64 * j];
    if (lane < 32) l4[lane + 768] = xr4[lane + 768];
    __syncthreads();

    // lane == t; unrolled v loop, part index compile-time
    const float* l = lds[wave] + lane * V_;
    float s[NP_], m[NP_];
    #pragma unroll
    for (int p = 0; p < NP_; ++p) { s[p] = 0.f; m[p] = -__builtin_huge_valf(); }
    #pragma unroll
    for (int v = 0; v < V_; ++v) {
        float val = l[v];
        s[PART_OF_V[v]] += val;
        m[PART_OF_V[v]] = fmaxf(m[PART_OF_V[v]], val);
    }

    // butterfly over 64 lanes
    #pragma unroll
    for (int p = 0; p < NP_; ++p) {
        #pragma unroll
        for (int off = 32; off > 0; off >>= 1) {
            s[p] += __shfl_xor(s[p], off);
            m[p] = fmaxf(m[p], __shfl_xor(m[p], off));
        }
    }

    if (lane == 0) {
        const int n = row >> 8, c = row & 255;
        #pragma unroll
        for (int p = 0; p < NP_; ++p) {
            avg_out[(n * NP_ + p) * C_ + c] = s[p] * INV_CNT[p];
            max_out[(n * NP_ + p) * C_ + c] = m[p];
        }
    }
}

// ---------------------------------------------------------------------------
// Kernel B: gate[(n,p),c] = sigmoid( W2@(relu(W1@avg+b1)+relu(W1@mx+b1)) + 2*b2 )
// One block per (n,p); 256 threads.
// ---------------------------------------------------------------------------
__global__ __launch_bounds__(256) void mlp_kernel(
    const float* __restrict__ avg, const float* __restrict__ mx,
    const float* __restrict__ W1, const float* __restrict__ b1,
    const float* __restrict__ W2, const float* __restrict__ b2,
    float* __restrict__ gate) {
    const int np = blockIdx.x;       // n*10 + p
    const int p  = np % NP_;
    __shared__ float vec[2][C_];
    __shared__ float partial[256];
    __shared__ float hsum[H_];

    const int t = threadIdx.x;
    vec[0][t] = avg[np * C_ + t];
    vec[1][t] = mx[np * C_ + t];
    __syncthreads();

    // partial dot: thread t = (chunk<<5) | (h<<1) | which ; 32 elements each
    const int which = t & 1, h = (t >> 1) & 15, chunk = t >> 5;
    const float* w1row = W1 + (p * H_ + h) * C_ + chunk * 32;
    const float* vv = vec[which] + chunk * 32;
    float acc = 0.f;
    #pragma unroll
    for (int k = 0; k < 32; ++k) acc += w1row[k] * vv[k];
    partial[t] = acc;
    __syncthreads();

    if (t < 32) {
        float a = b1[p * H_ + h];
        #pragma unroll
        for (int j = 0; j < 8; ++j) a += partial[t + 32 * j];
        a = fmaxf(a, 0.f);                       // relu
        if (which == 0) hsum[h] = a;
    }
    __syncthreads();
    if (t < 32 && (t & 1) == 1) {
        float a = b1[p * H_ + h];
        #pragma unroll
        for (int j = 0; j < 8; ++j) a += partial[t + 32 * j];
        hsum[h] += fmaxf(a, 0.f);
    }
    __syncthreads();

    // second layer: thread t = channel c
    const float4* w2row = (const float4*)(W2 + (p * C_ + t) * H_);
    float z = 2.f * b2[p * C_ + t];
    #pragma unroll
    for (int q = 0; q < 4; ++q) {
        float4 w = w2row[q];
        z += w.x * hsum[4*q] + w.y * hsum[4*q+1] + w.z * hsum[4*q+2] + w.w * hsum[4*q+3];
    }
    gate[np * C_ + t] = 1.f / (1.f + __expf(-z));
}

// ---------------------------------------------------------------------------
// Kernel C: out[n,c,t,w] = x[n,c,t,SRC_V[w]] * gate[n, PART_W[w], c]
// float4 stores, gathered reads (within the same 200B window).
// ---------------------------------------------------------------------------
__global__ __launch_bounds__(256) void scale_kernel(
    const float* __restrict__ x, const float* __restrict__ gate,
    float* __restrict__ out) {
    const unsigned u = blockIdx.x * 256u + threadIdx.x;  // float4 index
    const unsigned base = u * 4u;                        // out flat element idx
    const unsigned row  = base / (unsigned)ROW_;         // n*256 + c
    const unsigned r    = base - row * (unsigned)ROW_;
    const unsigned n = row >> 8, c = row & 255u;

    const float* xrow = x + (size_t)row * ROW_;
    const float* grow = gate + (n * NP_) * C_ + c;       // + p*256 per part

    const unsigned t0 = r / (unsigned)V_;
    const unsigned w0 = r - t0 * (unsigned)V_;

    float res[4];
    #pragma unroll
    for (int k = 0; k < 4; ++k) {
        unsigned w = w0 + k, t = t0;
        if (w >= V_) { w -= V_; t += 1; }
        res[k] = xrow[t * V_ + SRC_V[w]] * grow[PART_W[w] * C_];
    }
    float4 o; o.x = res[0]; o.y = res[1]; o.z = res[2]; o.w = res[3];
    ((float4*)out)[u] = o;
}

// ---------------------------------------------------------------------------
extern "C" void kernel_launch(void* const* d_in, const int* in_sizes, int n_in,
                              void* d_out, int out_size, void* d_ws, size_t ws_size,
                              hipStream_t stream) {
    const float* x  = (const float*)d_in[0];
    const float* W1 = (const float*)d_in[1];
    const float* b1 = (const float*)d_in[2];
    const float* W2 = (const float*)d_in[3];
    const float* b2 = (const float*)d_in[4];
    float* out = (float*)d_out;

    float* avg  = (float*)d_ws;            // NPC_ floats
    float* mx   = avg + NPC_;              // NPC_ floats
    float* gate = mx + NPC_;               // NPC_ floats

    reduce_kernel<<<NC_ / 4, 256, 0, stream>>>(x, avg, mx);
    mlp_kernel<<<N_ * NP_, 256, 0, stream>>>(avg, mx, W1, b1, W2, b2, gate);
    scale_kernel<<<(N_ * C_ * T_ * V_) / (4 * 256), 256, 0, stream>>>(x, gate, out);
}

// Round 2
// 407.370 us; speedup vs baseline: 1.2599x; 1.2599x over previous
//
#include <hip/hip_runtime.h>

// Problem constants: x (N=64, C=256, T=64, V=50) fp32; H=16; 10 parts.
#define N_  64
#define C_  256
#define T_  64
#define V_  50
#define H_  16
#define NP_ 10
#define ROW_ (T_ * V_)          // 3200 floats per (n,c) row
#define NC_  (N_ * C_)          // 16384 rows
#define NPC_ (N_ * NP_ * C_)    // 163840 floats per ws array

// part of each source vertex v (compile-time folded in unrolled loop)
constexpr int PART_OF_V[V_] = {
    0,0,0,0, 3,3,3,3, 1,1,1,1, 4,4,4,4, 2,2,2,2, 0, 3,3, 1,1,
    5,5,5,5, 8,8,8,8, 6,6,6,6, 9,9,9,9, 7,7,7,7, 5, 8,8, 6,6};

// 1 / (T * |part p|); sizes = {5,6,4,6,4,5,6,4,6,4}
constexpr float INV_CNT[NP_] = {
    1.f/320, 1.f/384, 1.f/256, 1.f/384, 1.f/256,
    1.f/320, 1.f/384, 1.f/256, 1.f/384, 1.f/256};

// out column w -> source v (concat of PARTS) and part of w (runtime-indexed)
__device__ const int SRC_V[V_] = {
    0,1,2,3,20,  8,9,10,11,23,24,  16,17,18,19,  4,5,6,7,21,22,  12,13,14,15,
    25,26,27,28,45,  33,34,35,36,48,49,  41,42,43,44,  29,30,31,32,46,47,  37,38,39,40};
__device__ const int PART_W[V_] = {
    0,0,0,0,0, 1,1,1,1,1,1, 2,2,2,2, 3,3,3,3,3,3, 4,4,4,4,
    5,5,5,5,5, 6,6,6,6,6,6, 7,7,7,7, 8,8,8,8,8,8, 9,9,9,9};

// ---------------------------------------------------------------------------
// Kernel A: per-(n,c) row, per-part sum & max over (T, V_p).
// One wave per row; 4 waves per block.  (unchanged from R0)
// ---------------------------------------------------------------------------
__global__ __launch_bounds__(256) void reduce_kernel(
    const float* __restrict__ x,
    float* __restrict__ avg_out,     // [(n*10+p)*256 + c]
    float* __restrict__ max_out) {
    __shared__ float lds[4][ROW_];
    const int wave = threadIdx.x >> 6;
    const int lane = threadIdx.x & 63;
    const int row  = blockIdx.x * 4 + wave;          // n*256 + c

    // coalesced float4 stage: 800 float4 per row
    const float4* xr4 = (const float4*)(x + (size_t)row * ROW_);
    float4* l4 = (float4*)lds[wave];
    #pragma unroll
    for (int j = 0; j < 12; ++j) l4[lane + 64 * j] = xr4[lane + 64 * j];
    if (lane < 32) l4[lane + 768] = xr4[lane + 768];
    __syncthreads();

    // lane == t; unrolled v loop, part index compile-time
    const float* l = lds[wave] + lane * V_;
    float s[NP_], m[NP_];
    #pragma unroll
    for (int p = 0; p < NP_; ++p) { s[p] = 0.f; m[p] = -__builtin_huge_valf(); }
    #pragma unroll
    for (int v = 0; v < V_; ++v) {
        float val = l[v];
        s[PART_OF_V[v]] += val;
        m[PART_OF_V[v]] = fmaxf(m[PART_OF_V[v]], val);
    }

    // butterfly over 64 lanes
    #pragma unroll
    for (int p = 0; p < NP_; ++p) {
        #pragma unroll
        for (int off = 32; off > 0; off >>= 1) {
            s[p] += __shfl_xor(s[p], off);
            m[p] = fmaxf(m[p], __shfl_xor(m[p], off));
        }
    }

    if (lane == 0) {
        const int n = row >> 8, c = row & 255;
        #pragma unroll
        for (int p = 0; p < NP_; ++p) {
            avg_out[(n * NP_ + p) * C_ + c] = s[p] * INV_CNT[p];
            max_out[(n * NP_ + p) * C_ + c] = m[p];
        }
    }
}

// ---------------------------------------------------------------------------
// Kernel B: gate[(n,p),c] = sigmoid( W2@(relu(W1@avg+b1)+relu(W1@mx+b1)) + 2*b2 )
// One block per (n,p); 256 threads.  (unchanged from R0)
// ---------------------------------------------------------------------------
__global__ __launch_bounds__(256) void mlp_kernel(
    const float* __restrict__ avg, const float* __restrict__ mx,
    const float* __restrict__ W1, const float* __restrict__ b1,
    const float* __restrict__ W2, const float* __restrict__ b2,
    float* __restrict__ gate) {
    const int np = blockIdx.x;       // n*10 + p
    const int p  = np % NP_;
    __shared__ float vec[2][C_];
    __shared__ float partial[256];
    __shared__ float hsum[H_];

    const int t = threadIdx.x;
    vec[0][t] = avg[np * C_ + t];
    vec[1][t] = mx[np * C_ + t];
    __syncthreads();

    // partial dot: thread t = (chunk<<5) | (h<<1) | which ; 32 elements each
    const int which = t & 1, h = (t >> 1) & 15, chunk = t >> 5;
    const float* w1row = W1 + (p * H_ + h) * C_ + chunk * 32;
    const float* vv = vec[which] + chunk * 32;
    float acc = 0.f;
    #pragma unroll
    for (int k = 0; k < 32; ++k) acc += w1row[k] * vv[k];
    partial[t] = acc;
    __syncthreads();

    if (t < 32) {
        float a = b1[p * H_ + h];
        #pragma unroll
        for (int j = 0; j < 8; ++j) a += partial[t + 32 * j];
        a = fmaxf(a, 0.f);                       // relu
        if (which == 0) hsum[h] = a;
    }
    __syncthreads();
    if (t < 32 && (t & 1) == 1) {
        float a = b1[p * H_ + h];
        #pragma unroll
        for (int j = 0; j < 8; ++j) a += partial[t + 32 * j];
        hsum[h] += fmaxf(a, 0.f);
    }
    __syncthreads();

    // second layer: thread t = channel c
    const float4* w2row = (const float4*)(W2 + (p * C_ + t) * H_);
    float z = 2.f * b2[p * C_ + t];
    #pragma unroll
    for (int q = 0; q < 4; ++q) {
        float4 w = w2row[q];
        z += w.x * hsum[4*q] + w.y * hsum[4*q+1] + w.z * hsum[4*q+2] + w.w * hsum[4*q+3];
    }
    gate[np * C_ + t] = 1.f / (1.f + __expf(-z));
}

// ---------------------------------------------------------------------------
// Kernel C (REWRITTEN): one block per (n,c) row. Stage the 3200-float row
// into LDS with coalesced float4 loads, gather the V-permutation from LDS,
// emit coalesced float4 stores. Gate values per output column precomputed
// into a 50-entry LDS table.
// ---------------------------------------------------------------------------
__global__ __launch_bounds__(256) void scale_kernel(
    const float* __restrict__ x, const float* __restrict__ gate,
    float* __restrict__ out) {
    __shared__ float lx[ROW_];       // 12.8 KB staged row
    __shared__ float gl[V_ + 2];     // per-output-column gate

    const int row = blockIdx.x;              // n*256 + c
    const int n = row >> 8, c = row & 255;
    const int tid = threadIdx.x;

    // ---- stage: 800 float4 = 256*3 + 32
    const float4* src = (const float4*)(x + (size_t)row * ROW_);
    float4* l4 = (float4*)lx;
    l4[tid]       = src[tid];
    l4[tid + 256] = src[tid + 256];
    l4[tid + 512] = src[tid + 512];
    if (tid < 32) l4[tid + 768] = src[tid + 768];
    if (tid < V_) gl[tid] = gate[(n * NP_ + PART_W[tid]) * C_ + c];
    __syncthreads();

    // ---- emit: 800 float4 outputs, same 256*3+32 split
    float4* dst = (float4*)(out + (size_t)row * ROW_);
    #pragma unroll
    for (int rep = 0; rep < 4; ++rep) {
        const int u = tid + rep * 256;       // float4 index within row
        if (rep == 3 && tid >= 32) break;
        const int base = u * 4;
        const int t0 = base / V_;
        const int w0 = base - t0 * V_;
        float res[4];
        #pragma unroll
        for (int k = 0; k < 4; ++k) {
            int w = w0 + k, t = t0;
            if (w >= V_) { w -= V_; t += 1; }
            res[k] = lx[t * V_ + SRC_V[w]] * gl[w];
        }
        float4 o; o.x = res[0]; o.y = res[1]; o.z = res[2]; o.w = res[3];
        dst[u] = o;
    }
}

// ---------------------------------------------------------------------------
extern "C" void kernel_launch(void* const* d_in, const int* in_sizes, int n_in,
                              void* d_out, int out_size, void* d_ws, size_t ws_size,
                              hipStream_t stream) {
    const float* x  = (const float*)d_in[0];
    const float* W1 = (const float*)d_in[1];
    const float* b1 = (const float*)d_in[2];
    const float* W2 = (const float*)d_in[3];
    const float* b2 = (const float*)d_in[4];
    float* out = (float*)d_out;

    float* avg  = (float*)d_ws;            // NPC_ floats
    float* mx   = avg + NPC_;              // NPC_ floats
    float* gate = mx + NPC_;               // NPC_ floats

    reduce_kernel<<<NC_ / 4, 256, 0, stream>>>(x, avg, mx);
    mlp_kernel<<<N_ * NP_, 256, 0, stream>>>(avg, mx, W1, b1, W2, b2, gate);
    scale_kernel<<<NC_, 256, 0, stream>>>(x, gate, out);
}